// Round 6
// baseline (384.680 us; speedup 1.0000x reference)
//
#include <hip/hip_runtime.h>

// GIN 2-layer forward, MI355X (gfx950). Round 17:
//  - gather reverted to round-14/15 proven form (56us; wide-load r16
//    regressed: 2 structures both plateau 3.1-3.4 TB/s => structural
//    ceiling for random 256B rows; stop touching).
//  - CSR rebuilt as direct scatter, ebuf ELIMINATED. Round-5 counters:
//    binA WRITE_SIZE=37MB for 6.4MB payload (random 8B scatter line
//    amplification) at ~600GB/s was the limiter. New: binA counts only;
//    binS scans -> offs/cur; binC scatters csr_col (4B randoms into a
//    3.2MB L2-resident array -> write-back coalesces).

#define N_NODES 50000
#define N_EDGES 800000
#define DIM 128
#define BN_EPS 1e-5f
#define GEMM_GRID 782           // ceil(N_NODES/64)
#define NBUCK 256
#define NPB 196                 // nodes per bucket
#define BINA_BLOCKS 800
#define EPB 1000                // 800 * 1000 = 800000 exact
#define NSLOT 16                // stats atomic slots

using bfrag8 = __attribute__((ext_vector_type(8))) short;
using accf4  = __attribute__((ext_vector_type(4))) float;

__device__ __forceinline__ float bf2f(unsigned short u) {
  union { unsigned u32; float f; } c;
  c.u32 = ((unsigned)u) << 16;
  return c.f;
}
__device__ __forceinline__ unsigned short f2bf(float f) {
  union { float f; unsigned u32; } c;
  c.f = f;
  unsigned u = c.u32;
  return (unsigned short)((u + 0x7fffu + ((u >> 16) & 1u)) >> 16);  // RNE
}

// ---- prep: detect dtype, pack weights, convert vectors, zero scratch ----
struct PPtrs { const void* xs; const void* w[4]; const void* v[10]; };

__global__ __launch_bounds__(256) void prep_kernel(
    PPtrs pp, unsigned short* __restrict__ PW, float* __restrict__ PV,
    int* __restrict__ flag, float* __restrict__ ps2, int* __restrict__ deg) {
  __shared__ int oks[64];
  __shared__ int bfs;
  int t = threadIdx.x;
  if (t < 64) {
    unsigned short u = ((const unsigned short*)pp.xs)[t * 2];
    int e = (u >> 7) & 0xFF;
    oks[t] = ((e >= 96 && e <= 134) || ((u & 0x7FFFu) == 0)) ? 1 : 0;
  }
  __syncthreads();
  if (t == 0) {
    int c = 0;
    for (int i = 0; i < 64; ++i) c += oks[i];
    bfs = (c >= 56) ? 1 : 0;
  }
  __syncthreads();
  int bf = bfs;
  int b = blockIdx.x;

  if (b < 4) {
    const void* src = pp.w[b];
    unsigned short* dst = PW + (size_t)b * 16384;
    for (int f = t; f < 2048; f += 256) {
      int kt = f >> 9, nt = (f >> 6) & 7, lane = f & 63;
      int kbase = kt * 32 + (lane >> 4) * 8;
      int n = nt * 16 + (lane & 15);
      unsigned short tmp[8];
      for (int j = 0; j < 8; ++j) {
        int idx = (kbase + j) * DIM + n;
        if (bf) tmp[j] = ((const unsigned short*)src)[idx];
        else    tmp[j] = f2bf(((const float*)src)[idx]);
      }
      for (int j = 0; j < 8; ++j) dst[f * 8 + j] = tmp[j];
    }
  } else if (b == 4) {
    for (int j = t; j < 10 * DIM; j += 256) {
      int vec = j >> 7, idx = j & 127;
      float v;
      if (bf) v = bf2f(((const unsigned short*)pp.v[vec])[idx]);
      else    v = ((const float*)pp.v[vec])[idx];
      PV[j] = v;
    }
    if (t == 0) *flag = bf;
    for (int j = t; j < 3 * NSLOT * 256; j += 256) ps2[j] = 0.f;
  } else {
    // blocks 5..39 zero deg[N] + bcnt[NBUCK] (contiguous)
    const int total = N_NODES + NBUCK;
    for (int i = (b - 5) * 256 + t; i < total; i += 35 * 256) deg[i] = 0;
  }
}

// ================= CSR build: count -> scan -> scatter =================
__global__ __launch_bounds__(256) void binA_kernel(
    const int* __restrict__ row, int* __restrict__ deg,
    int* __restrict__ bcnt) {
  __shared__ int hist[NBUCK];
  int t = threadIdx.x;
  int e0 = blockIdx.x * EPB;
  hist[t] = 0;
  __syncthreads();
  for (int i = t; i < EPB; i += 256) {
    int r = row[e0 + i];
    atomicAdd(&deg[r], 1);
    atomicAdd(&hist[r / NPB], 1);
  }
  __syncthreads();
  int h = hist[t];
  if (h) atomicAdd(&bcnt[t], h);
}

__global__ __launch_bounds__(256) void binS_kernel(
    const int* __restrict__ deg, const int* __restrict__ bcnt,
    int* __restrict__ offs, int* __restrict__ cur) {
  __shared__ int sc[256];
  __shared__ int dg[256];
  int b = blockIdx.x;
  int t = threadIdx.x;

  sc[t] = bcnt[t];
  __syncthreads();
  for (int d = 1; d < 256; d <<= 1) {
    int v = (t >= d) ? sc[t - d] : 0;
    __syncthreads();
    sc[t] += v;
    __syncthreads();
  }
  int segbase = (b == 0) ? 0 : sc[b - 1];

  int nb = b * NPB;
  int nend = nb + NPB;
  if (nend > N_NODES) nend = N_NODES;
  int nn = nend - nb;

  int myd = (t < nn) ? deg[nb + t] : 0;
  dg[t] = myd;
  __syncthreads();
  for (int d = 1; d < 256; d <<= 1) {
    int v = (t >= d) ? dg[t - d] : 0;
    __syncthreads();
    dg[t] += v;
    __syncthreads();
  }
  int excl = segbase + dg[t] - myd;
  if (t < nn) {
    offs[nb + t] = excl;
    cur[nb + t] = excl;
  }
  if (b == NBUCK - 1 && t == 0) offs[N_NODES] = N_EDGES;
}

__global__ __launch_bounds__(256) void binC_kernel(
    const int* __restrict__ row, const int* __restrict__ col,
    int* __restrict__ cur, int* __restrict__ csr_col) {
  int e0 = blockIdx.x * EPB;
  for (int i = threadIdx.x; i < EPB; i += 256) {
    int r = row[e0 + i];
    int pos = atomicAdd(&cur[r], 1);
    csr_col[pos] = col[e0 + i];
  }
}

// ================= full-row gather, unroll-16 (proven 56us form) =========
// Wave = 1 node; lane owns 2 channels (4B) => one wave instruction reads
// the whole 256B feature row of one neighbor. mode 0: plain sum; mode 1:
// relu(v*sc+sh) from slotted stats + g/be.
__global__ __launch_bounds__(256, 4) void gather_row_kernel(
    const void* __restrict__ src, const int* __restrict__ offs,
    const int* __restrict__ csr_col, const float* __restrict__ stats_in,
    const float* __restrict__ gv, const float* __restrict__ bev,
    unsigned short* __restrict__ agg, const int* __restrict__ flagp,
    int mode) {
  __shared__ float ssl[256];
  int tid = threadIdx.x;
  if (mode == 1) {
    if (tid < 128) {
      float s = 0.f, q = 0.f;
#pragma unroll
      for (int k = 0; k < NSLOT; ++k) {
        s += stats_in[k * 256 + tid];
        q += stats_in[k * 256 + 128 + tid];
      }
      const float invN = 1.0f / (float)N_NODES;
      float m = s * invN;
      float v = q * invN - m * m;
      float scv = gv[tid] * rsqrtf(v + BN_EPS);
      ssl[tid] = scv;
      ssl[128 + tid] = bev[tid] - m * scv;
    }
    __syncthreads();
  }

  int node = blockIdx.x * 4 + (tid >> 6);
  if (node >= N_NODES) return;
  int lane = tid & 63;
  int ch = lane * 2;
  int start = offs[node], end = offs[node + 1];
  float a0 = 0.f, a1 = 0.f;
  int bf = *flagp;
  float sc0 = 0.f, sc1 = 0.f, sh0 = 0.f, sh1 = 0.f;
  if (mode == 1) {
    sc0 = ssl[ch]; sc1 = ssl[ch + 1];
    sh0 = ssl[128 + ch]; sh1 = ssl[128 + ch + 1];
  }

  if (mode == 1 || bf) {
    const unsigned short* h = (const unsigned short*)src;
    int j = start;
    for (; j + 15 < end; j += 16) {
      int ix[16];
#pragma unroll
      for (int k = 0; k < 16; ++k) ix[k] = csr_col[j + k];
      unsigned u[16];
#pragma unroll
      for (int k = 0; k < 16; ++k)
        u[k] = *(const unsigned*)(h + (size_t)ix[k] * DIM + ch);
      if (mode == 1) {
#pragma unroll
        for (int k = 0; k < 16; ++k) {
          a0 += fmaxf(bf2f((unsigned short)u[k]) * sc0 + sh0, 0.f);
          a1 += fmaxf(bf2f((unsigned short)(u[k] >> 16)) * sc1 + sh1, 0.f);
        }
      } else {
#pragma unroll
        for (int k = 0; k < 16; ++k) {
          a0 += bf2f((unsigned short)u[k]);
          a1 += bf2f((unsigned short)(u[k] >> 16));
        }
      }
    }
    if (j + 7 < end) {
      int ix[8];
#pragma unroll
      for (int k = 0; k < 8; ++k) ix[k] = csr_col[j + k];
      unsigned u[8];
#pragma unroll
      for (int k = 0; k < 8; ++k)
        u[k] = *(const unsigned*)(h + (size_t)ix[k] * DIM + ch);
#pragma unroll
      for (int k = 0; k < 8; ++k) {
        if (mode == 1) {
          a0 += fmaxf(bf2f((unsigned short)u[k]) * sc0 + sh0, 0.f);
          a1 += fmaxf(bf2f((unsigned short)(u[k] >> 16)) * sc1 + sh1, 0.f);
        } else {
          a0 += bf2f((unsigned short)u[k]);
          a1 += bf2f((unsigned short)(u[k] >> 16));
        }
      }
      j += 8;
    }
    if (j + 3 < end) {
      int ix[4];
#pragma unroll
      for (int k = 0; k < 4; ++k) ix[k] = csr_col[j + k];
      unsigned u[4];
#pragma unroll
      for (int k = 0; k < 4; ++k)
        u[k] = *(const unsigned*)(h + (size_t)ix[k] * DIM + ch);
#pragma unroll
      for (int k = 0; k < 4; ++k) {
        if (mode == 1) {
          a0 += fmaxf(bf2f((unsigned short)u[k]) * sc0 + sh0, 0.f);
          a1 += fmaxf(bf2f((unsigned short)(u[k] >> 16)) * sc1 + sh1, 0.f);
        } else {
          a0 += bf2f((unsigned short)u[k]);
          a1 += bf2f((unsigned short)(u[k] >> 16));
        }
      }
      j += 4;
    }
    for (; j < end; ++j) {
      unsigned u = *(const unsigned*)(h + (size_t)csr_col[j] * DIM + ch);
      if (mode == 1) {
        a0 += fmaxf(bf2f((unsigned short)u) * sc0 + sh0, 0.f);
        a1 += fmaxf(bf2f((unsigned short)(u >> 16)) * sc1 + sh1, 0.f);
      } else {
        a0 += bf2f((unsigned short)u);
        a1 += bf2f((unsigned short)(u >> 16));
      }
    }
  } else {
    const float* x = (const float*)src;
    int j = start;
    for (; j + 7 < end; j += 8) {
      int ix[8];
#pragma unroll
      for (int k = 0; k < 8; ++k) ix[k] = csr_col[j + k];
#pragma unroll
      for (int k = 0; k < 8; ++k) {
        float2 v = *(const float2*)(x + (size_t)ix[k] * DIM + ch);
        a0 += v.x; a1 += v.y;
      }
    }
    for (; j < end; ++j) {
      float2 v = *(const float2*)(x + (size_t)csr_col[j] * DIM + ch);
      a0 += v.x; a1 += v.y;
    }
  }
  unsigned o = (unsigned)f2bf(a0) | ((unsigned)f2bf(a1) << 16);
  *(unsigned*)(agg + (size_t)node * DIM + ch) = o;
}

// ================= MFMA GEMM (+BN transform in, +slotted stats out) ======
__global__ __launch_bounds__(256) void gemm_kernel(
    const void* __restrict__ Ap, const unsigned short* __restrict__ agg,
    const unsigned short* __restrict__ PWm, const float* __restrict__ bias,
    const float* __restrict__ stats_in, const float* __restrict__ gv,
    const float* __restrict__ bev, void* __restrict__ Cp,
    float* __restrict__ stats_out, const int* __restrict__ flagp,
    int a_ext, int add_agg, int out_ext) {
  __shared__ unsigned short As[64 * 136];
  __shared__ float red_s[256];
  __shared__ float red_q[256];
  __shared__ float ssl[256];
  const int tid = threadIdx.x;
  const int row0 = blockIdx.x * 64;
  const int bf = *flagp;
  const int has_tf = (stats_in != nullptr);

  if (has_tf) {
    if (tid < 128) {
      float s = 0.f, q = 0.f;
#pragma unroll
      for (int k = 0; k < NSLOT; ++k) {
        s += stats_in[k * 256 + tid];
        q += stats_in[k * 256 + 128 + tid];
      }
      const float invN = 1.0f / (float)N_NODES;
      float m = s * invN;
      float v = q * invN - m * m;
      float scv = gv[tid] * rsqrtf(v + BN_EPS);
      ssl[tid] = scv;
      ssl[128 + tid] = bev[tid] - m * scv;
    }
    __syncthreads();
  }

  for (int i = 0; i < 8; ++i) {
    int G = tid + i * 256;
    int lrow = G >> 5;
    int ch = (G & 31) * 4;
    int grow = row0 + lrow;
    float4 v = make_float4(0.f, 0.f, 0.f, 0.f);
    if (grow < N_NODES) {
      if (a_ext && !bf) {
        v = *(const float4*)((const float*)Ap + (size_t)grow * DIM + ch);
      } else {
        ushort4 u = *(const ushort4*)((const unsigned short*)Ap +
                                      (size_t)grow * DIM + ch);
        v = make_float4(bf2f(u.x), bf2f(u.y), bf2f(u.z), bf2f(u.w));
      }
      if (has_tf) {
        float4 sc = *(const float4*)&ssl[ch];
        float4 sh = *(const float4*)&ssl[128 + ch];
        v.x = fmaxf(v.x * sc.x + sh.x, 0.f);
        v.y = fmaxf(v.y * sc.y + sh.y, 0.f);
        v.z = fmaxf(v.z * sc.z + sh.z, 0.f);
        v.w = fmaxf(v.w * sc.w + sh.w, 0.f);
      }
      if (add_agg) {
        ushort4 au = *(const ushort4*)(agg + (size_t)grow * DIM + ch);
        v.x += bf2f(au.x); v.y += bf2f(au.y);
        v.z += bf2f(au.z); v.w += bf2f(au.w);
      }
    }
    ushort4 o;
    o.x = f2bf(v.x); o.y = f2bf(v.y); o.z = f2bf(v.z); o.w = f2bf(v.w);
    *(ushort4*)&As[lrow * 136 + ch] = o;
  }
  __syncthreads();

  const int wv = tid >> 6, lane = tid & 63;
  const int quad = lane >> 4, lo = lane & 15;
  accf4 acc[8];
#pragma unroll
  for (int nt = 0; nt < 8; ++nt) {
    acc[nt][0] = 0.f; acc[nt][1] = 0.f; acc[nt][2] = 0.f; acc[nt][3] = 0.f;
  }
#pragma unroll
  for (int kt = 0; kt < 4; ++kt) {
    bfrag8 a = *(const bfrag8*)&As[(wv * 16 + lo) * 136 + kt * 32 + quad * 8];
    const unsigned short* pw = PWm + kt * 4096 + lane * 8;
#pragma unroll
    for (int nt = 0; nt < 8; ++nt) {
      bfrag8 b = *(const bfrag8*)(pw + nt * 512);
      acc[nt] = __builtin_amdgcn_mfma_f32_16x16x32_bf16(a, b, acc[nt], 0, 0, 0);
    }
  }
  __syncthreads();

  if (out_ext && !bf) {
    float* Co = (float*)Cp;
#pragma unroll
    for (int nt = 0; nt < 8; ++nt) {
      float b = bias[nt * 16 + lo];
#pragma unroll
      for (int reg = 0; reg < 4; ++reg) {
        int grow = row0 + wv * 16 + quad * 4 + reg;
        if (grow < N_NODES)
          Co[(size_t)grow * DIM + nt * 16 + lo] = acc[nt][reg] + b;
      }
    }
  } else {
#pragma unroll
    for (int nt = 0; nt < 8; ++nt) {
      float b = bias[nt * 16 + lo];
#pragma unroll
      for (int reg = 0; reg < 4; ++reg) {
        As[(wv * 16 + quad * 4 + reg) * 136 + nt * 16 + lo] =
            f2bf(acc[nt][reg] + b);
      }
    }
    __syncthreads();
    unsigned short* Co = (unsigned short*)Cp;
    for (int i = 0; i < 8; ++i) {
      int G = tid + i * 256;
      int lrow = G >> 5, ch = (G & 31) * 4;
      int grow = row0 + lrow;
      if (grow < N_NODES)
        *(ushort4*)(Co + (size_t)grow * DIM + ch) =
            *(const ushort4*)&As[lrow * 136 + ch];
    }
    if (stats_out) {
      int c = tid & 127, rh = tid >> 7;
      int rmax = N_NODES - row0;
      if (rmax > 64) rmax = 64;
      int rend = rh * 32 + 32;
      if (rend > rmax) rend = rmax;
      float s = 0.f, q = 0.f;
      for (int r = rh * 32; r < rend; ++r) {
        float v = bf2f(As[r * 136 + c]);
        s += v; q += v * v;
      }
      red_s[tid] = s; red_q[tid] = q;
      __syncthreads();
      if (tid < 128) {
        float* so = stats_out + (size_t)(blockIdx.x & (NSLOT - 1)) * 256;
        atomicAdd(so + tid, red_s[tid] + red_s[tid + 128]);
        atomicAdd(so + 128 + tid, red_q[tid] + red_q[tid + 128]);
      }
    }
  }
}

extern "C" void kernel_launch(void* const* d_in, const int* in_sizes, int n_in,
                              void* d_out, int out_size, void* d_ws, size_t ws_size,
                              hipStream_t stream) {
  const void* x  = d_in[0];
  const int* row = (const int*)d_in[1];
  const int* col = (const int*)d_in[2];

  const size_t ND = (size_t)N_NODES * DIM;
  unsigned short* agg = (unsigned short*)d_ws;        // ND bf16
  unsigned short* hA  = agg + ND;                     // ND bf16
  unsigned short* hB  = hA + ND;                      // ND bf16
  unsigned short* PW  = hB + ND;                      // 4*16384 bf16
  float* PV    = (float*)(PW + 4 * 16384);            // 10*128 fp32
  float* ps2   = PV + 10 * DIM;                       // 3*NSLOT*256 fp32
  int*   flag  = (int*)(ps2 + 3 * NSLOT * 256);       // 1 (+pad)
  int*   deg   = flag + 4;                            // N
  int*   bcnt  = deg + N_NODES;                       // NBUCK (contiguous!)
  int*   offs  = bcnt + NBUCK;                        // N+1
  int*   cur   = offs + N_NODES + 1;                  // N
  int*   csr_col = cur + N_NODES;                     // E

  float* S0 = ps2 + 0 * NSLOT * 256;
  float* S1 = ps2 + 1 * NSLOT * 256;
  float* S2 = ps2 + 2 * NSLOT * 256;

  float* c0_b1f = PV + 0 * DIM; float* c0_gf  = PV + 1 * DIM;
  float* c0_bef = PV + 2 * DIM; float* c0_b2f = PV + 3 * DIM;
  float* bn0_gf = PV + 4 * DIM; float* bn0_bef= PV + 5 * DIM;
  float* c1_b1f = PV + 6 * DIM; float* c1_gf  = PV + 7 * DIM;
  float* c1_bef = PV + 8 * DIM; float* c1_b2f = PV + 9 * DIM;

  const int grow_grid = (N_NODES + 3) / 4;  // 12500

  PPtrs pp;
  pp.xs = x;
  pp.w[0] = d_in[3];  pp.w[1] = d_in[7];  pp.w[2] = d_in[11]; pp.w[3] = d_in[15];
  pp.v[0] = d_in[4];  pp.v[1] = d_in[5];  pp.v[2] = d_in[6];  pp.v[3] = d_in[8];
  pp.v[4] = d_in[9];  pp.v[5] = d_in[10]; pp.v[6] = d_in[12]; pp.v[7] = d_in[13];
  pp.v[8] = d_in[14]; pp.v[9] = d_in[16];

  // prep: detect + weights + vectors + flag + zero(ps2, deg, bcnt)
  prep_kernel<<<40, 256, 0, stream>>>(pp, PW, PV, flag, ps2, deg);

  // CSR build (3 dispatches, no ebuf)
  binA_kernel<<<BINA_BLOCKS, 256, 0, stream>>>(row, deg, bcnt);
  binS_kernel<<<NBUCK, 256, 0, stream>>>(deg, bcnt, offs, cur);
  binC_kernel<<<BINA_BLOCKS, 256, 0, stream>>>(row, col, cur, csr_col);

  // ---- conv0 ----
  gather_row_kernel<<<grow_grid, 256, 0, stream>>>(
      x, offs, csr_col, nullptr, nullptr, nullptr, agg, flag, 0);
  gemm_kernel<<<GEMM_GRID, 256, 0, stream>>>(
      x, agg, PW + 0 * 16384, c0_b1f, nullptr, nullptr, nullptr,
      hA, S0, flag, 1, 1, 0);
  gemm_kernel<<<GEMM_GRID, 256, 0, stream>>>(
      hA, nullptr, PW + 1 * 16384, c0_b2f, S0, c0_gf, c0_bef,
      hB, S1, flag, 0, 0, 0);

  // ---- conv1 ----
  gather_row_kernel<<<grow_grid, 256, 0, stream>>>(
      hB, offs, csr_col, S1, bn0_gf, bn0_bef, agg, flag, 1);
  gemm_kernel<<<GEMM_GRID, 256, 0, stream>>>(
      hB, agg, PW + 2 * 16384, c1_b1f, S1, bn0_gf, bn0_bef,
      hA, S2, flag, 0, 1, 0);
  gemm_kernel<<<GEMM_GRID, 256, 0, stream>>>(
      hA, nullptr, PW + 3 * 16384, c1_b2f, S2, c1_gf, c1_bef,
      d_out, nullptr, flag, 0, 0, 1);
}

// Round 7
// 348.800 us; speedup vs baseline: 1.1029x; 1.1029x over previous
//
#include <hip/hip_runtime.h>

// GIN 2-layer forward, MI355X (gfx950). Round 18:
//  - CSR scatter rebuilt with LDS WRITE-COMBINING. Round-6 lesson: any
//    device-wide random small-store scatter amplifies ~16x (53MB writes
//    for 3.2MB payload; non-coherent XCD L2s migrate partial lines).
//    New binA: edges packed u32 (ids fit 16 bits), staged per-bucket in
//    LDS buf[256][32], flushed in 16-entry (64B, line-aligned) groups by
//    the bucket-owner thread -> every ebuf line leaves the CU full.
//  - binB: per-bucket LDS counting sort (packed u32), offs fused. binC
//    and binS eliminated.
//  - gather unchanged (round-15 proven form; 3.4TB/s structural ceiling).

#define N_NODES 50000
#define N_EDGES 800000
#define DIM 128
#define BN_EPS 1e-5f
#define GEMM_GRID 782           // ceil(N_NODES/64)
#define NBUCK 256
#define NPB 196                 // nodes per bucket
#define BCAP 4096               // max edges per bucket
#define BINA_BLOCKS 128
#define EPB 6250                // 128 * 6250 = 800000 exact
#define NSLOT 16                // stats atomic slots

using bfrag8 = __attribute__((ext_vector_type(8))) short;
using accf4  = __attribute__((ext_vector_type(4))) float;

__device__ __forceinline__ float bf2f(unsigned short u) {
  union { unsigned u32; float f; } c;
  c.u32 = ((unsigned)u) << 16;
  return c.f;
}
__device__ __forceinline__ unsigned short f2bf(float f) {
  union { float f; unsigned u32; } c;
  c.f = f;
  unsigned u = c.u32;
  return (unsigned short)((u + 0x7fffu + ((u >> 16) & 1u)) >> 16);  // RNE
}

// ---- prep: detect dtype, pack weights, convert vectors, zero scratch ----
struct PPtrs { const void* xs; const void* w[4]; const void* v[10]; };

__global__ __launch_bounds__(256) void prep_kernel(
    PPtrs pp, unsigned short* __restrict__ PW, float* __restrict__ PV,
    int* __restrict__ flag, float* __restrict__ ps2, int* __restrict__ deg) {
  __shared__ int oks[64];
  __shared__ int bfs;
  int t = threadIdx.x;
  if (t < 64) {
    unsigned short u = ((const unsigned short*)pp.xs)[t * 2];
    int e = (u >> 7) & 0xFF;
    oks[t] = ((e >= 96 && e <= 134) || ((u & 0x7FFFu) == 0)) ? 1 : 0;
  }
  __syncthreads();
  if (t == 0) {
    int c = 0;
    for (int i = 0; i < 64; ++i) c += oks[i];
    bfs = (c >= 56) ? 1 : 0;
  }
  __syncthreads();
  int bf = bfs;
  int b = blockIdx.x;

  if (b < 4) {
    const void* src = pp.w[b];
    unsigned short* dst = PW + (size_t)b * 16384;
    for (int f = t; f < 2048; f += 256) {
      int kt = f >> 9, nt = (f >> 6) & 7, lane = f & 63;
      int kbase = kt * 32 + (lane >> 4) * 8;
      int n = nt * 16 + (lane & 15);
      unsigned short tmp[8];
      for (int j = 0; j < 8; ++j) {
        int idx = (kbase + j) * DIM + n;
        if (bf) tmp[j] = ((const unsigned short*)src)[idx];
        else    tmp[j] = f2bf(((const float*)src)[idx]);
      }
      for (int j = 0; j < 8; ++j) dst[f * 8 + j] = tmp[j];
    }
  } else if (b == 4) {
    for (int j = t; j < 10 * DIM; j += 256) {
      int vec = j >> 7, idx = j & 127;
      float v;
      if (bf) v = bf2f(((const unsigned short*)pp.v[vec])[idx]);
      else    v = ((const float*)pp.v[vec])[idx];
      PV[j] = v;
    }
    if (t == 0) *flag = bf;
    for (int j = t; j < 3 * NSLOT * 256; j += 256) ps2[j] = 0.f;
  } else {
    // blocks 5..39 zero deg[N] + bcnt[NBUCK] + gcur[NBUCK] (contiguous)
    const int total = N_NODES + 2 * NBUCK;
    for (int i = (b - 5) * 256 + t; i < total; i += 35 * 256) deg[i] = 0;
  }
}

// ================= CSR build =================
// binA: count deg/bcnt + write-combined scatter of packed (r|c<<16) edges
// into per-bucket ebuf segments. Flushes are 16-u32 (64B) line-aligned
// groups written by the bucket-owner thread.
__global__ __launch_bounds__(256) void binA_kernel(
    const int* __restrict__ row, const int* __restrict__ col,
    int* __restrict__ deg, int* __restrict__ bcnt, int* __restrict__ gcur,
    unsigned* __restrict__ ebuf) {
  __shared__ int hist[NBUCK];
  __shared__ int cnt[NBUCK];
  __shared__ unsigned buf[NBUCK][32];
  int t = threadIdx.x;
  int e0 = blockIdx.x * EPB;
  hist[t] = 0;
  cnt[t] = 0;
  __syncthreads();

  for (int base = 0; base < EPB; base += 256) {
    int i = base + t;
    if (i < EPB) {
      int r = row[e0 + i];
      int c = col[e0 + i];
      atomicAdd(&deg[r], 1);
      int bk = r / NPB;
      atomicAdd(&hist[bk], 1);
      unsigned pk = (unsigned)r | ((unsigned)c << 16);
      int pos = atomicAdd(&cnt[bk], 1);
      if (pos < 32) {
        buf[bk][pos] = pk;
      } else {
        // rare overflow: direct spill (correctness path)
        int gp = atomicAdd(&gcur[bk], 1);
        ebuf[(size_t)bk * BCAP + gp] = pk;
      }
    }
    __syncthreads();
    // thread t owns bucket t: flush full 16-entry (64B) groups
    int c2 = cnt[t];
    if (c2 > 32) c2 = 32;
    if (c2 >= 16) {
      int nf = c2 & ~15;
      int gp = atomicAdd(&gcur[t], nf);
      unsigned* dst = ebuf + (size_t)t * BCAP + gp;
      for (int k = 0; k < nf; ++k) dst[k] = buf[t][k];
      int rem = c2 - nf;
      for (int k = 0; k < rem; ++k) buf[t][k] = buf[t][nf + k];
      cnt[t] = rem;
    } else {
      cnt[t] = c2;
    }
    __syncthreads();
  }
  // tail flush
  int c2 = cnt[t];
  if (c2 > 0) {
    int gp = atomicAdd(&gcur[t], c2);
    unsigned* dst = ebuf + (size_t)t * BCAP + gp;
    for (int k = 0; k < c2; ++k) dst[k] = buf[t][k];
  }
  int h = hist[t];
  if (h) atomicAdd(&bcnt[t], h);
}

// binB: redundant bcnt scan -> segbase; local deg scan -> offs; per-bucket
// LDS counting sort of packed edges; sequential csr_col write.
__global__ __launch_bounds__(256) void binB_kernel(
    const int* __restrict__ deg, const int* __restrict__ bcnt,
    const unsigned* __restrict__ ebuf, int* __restrict__ csr_col,
    int* __restrict__ offs) {
  __shared__ int sc[256];
  __shared__ int dg[256];
  __shared__ int cur[NPB];
  __shared__ int seg[BCAP];
  int b = blockIdx.x;
  int t = threadIdx.x;

  sc[t] = bcnt[t];
  __syncthreads();
  for (int d = 1; d < 256; d <<= 1) {
    int v = (t >= d) ? sc[t - d] : 0;
    __syncthreads();
    sc[t] += v;
    __syncthreads();
  }
  int segbase = (b == 0) ? 0 : sc[b - 1];

  int nb = b * NPB;
  int nend = nb + NPB;
  if (nend > N_NODES) nend = N_NODES;
  int nn = nend - nb;

  int myd = (t < nn) ? deg[nb + t] : 0;
  dg[t] = myd;
  __syncthreads();
  for (int d = 1; d < 256; d <<= 1) {
    int v = (t >= d) ? dg[t - d] : 0;
    __syncthreads();
    dg[t] += v;
    __syncthreads();
  }
  int excl = dg[t] - myd;        // local exclusive prefix
  if (t < nn) {
    offs[nb + t] = segbase + excl;
    cur[t] = excl;
  }
  if (b == NBUCK - 1 && t == 0) offs[N_NODES] = N_EDGES;
  __syncthreads();

  int cnt = bcnt[b];
  const unsigned* eb = ebuf + (size_t)b * BCAP;
  for (int i = t; i < cnt; i += 256) {
    unsigned e = eb[i];
    int r = (int)(e & 0xFFFFu);
    int slot = atomicAdd(&cur[r - nb], 1);
    seg[slot] = (int)(e >> 16);
  }
  __syncthreads();
  for (int i = t; i < cnt; i += 256)
    csr_col[segbase + i] = seg[i];
}

// ================= full-row gather, unroll-16 (proven 56us form) =========
__global__ __launch_bounds__(256, 4) void gather_row_kernel(
    const void* __restrict__ src, const int* __restrict__ offs,
    const int* __restrict__ csr_col, const float* __restrict__ stats_in,
    const float* __restrict__ gv, const float* __restrict__ bev,
    unsigned short* __restrict__ agg, const int* __restrict__ flagp,
    int mode) {
  __shared__ float ssl[256];
  int tid = threadIdx.x;
  if (mode == 1) {
    if (tid < 128) {
      float s = 0.f, q = 0.f;
#pragma unroll
      for (int k = 0; k < NSLOT; ++k) {
        s += stats_in[k * 256 + tid];
        q += stats_in[k * 256 + 128 + tid];
      }
      const float invN = 1.0f / (float)N_NODES;
      float m = s * invN;
      float v = q * invN - m * m;
      float scv = gv[tid] * rsqrtf(v + BN_EPS);
      ssl[tid] = scv;
      ssl[128 + tid] = bev[tid] - m * scv;
    }
    __syncthreads();
  }

  int node = blockIdx.x * 4 + (tid >> 6);
  if (node >= N_NODES) return;
  int lane = tid & 63;
  int ch = lane * 2;
  int start = offs[node], end = offs[node + 1];
  float a0 = 0.f, a1 = 0.f;
  int bf = *flagp;
  float sc0 = 0.f, sc1 = 0.f, sh0 = 0.f, sh1 = 0.f;
  if (mode == 1) {
    sc0 = ssl[ch]; sc1 = ssl[ch + 1];
    sh0 = ssl[128 + ch]; sh1 = ssl[128 + ch + 1];
  }

  if (mode == 1 || bf) {
    const unsigned short* h = (const unsigned short*)src;
    int j = start;
    for (; j + 15 < end; j += 16) {
      int ix[16];
#pragma unroll
      for (int k = 0; k < 16; ++k) ix[k] = csr_col[j + k];
      unsigned u[16];
#pragma unroll
      for (int k = 0; k < 16; ++k)
        u[k] = *(const unsigned*)(h + (size_t)ix[k] * DIM + ch);
      if (mode == 1) {
#pragma unroll
        for (int k = 0; k < 16; ++k) {
          a0 += fmaxf(bf2f((unsigned short)u[k]) * sc0 + sh0, 0.f);
          a1 += fmaxf(bf2f((unsigned short)(u[k] >> 16)) * sc1 + sh1, 0.f);
        }
      } else {
#pragma unroll
        for (int k = 0; k < 16; ++k) {
          a0 += bf2f((unsigned short)u[k]);
          a1 += bf2f((unsigned short)(u[k] >> 16));
        }
      }
    }
    if (j + 7 < end) {
      int ix[8];
#pragma unroll
      for (int k = 0; k < 8; ++k) ix[k] = csr_col[j + k];
      unsigned u[8];
#pragma unroll
      for (int k = 0; k < 8; ++k)
        u[k] = *(const unsigned*)(h + (size_t)ix[k] * DIM + ch);
#pragma unroll
      for (int k = 0; k < 8; ++k) {
        if (mode == 1) {
          a0 += fmaxf(bf2f((unsigned short)u[k]) * sc0 + sh0, 0.f);
          a1 += fmaxf(bf2f((unsigned short)(u[k] >> 16)) * sc1 + sh1, 0.f);
        } else {
          a0 += bf2f((unsigned short)u[k]);
          a1 += bf2f((unsigned short)(u[k] >> 16));
        }
      }
      j += 8;
    }
    if (j + 3 < end) {
      int ix[4];
#pragma unroll
      for (int k = 0; k < 4; ++k) ix[k] = csr_col[j + k];
      unsigned u[4];
#pragma unroll
      for (int k = 0; k < 4; ++k)
        u[k] = *(const unsigned*)(h + (size_t)ix[k] * DIM + ch);
#pragma unroll
      for (int k = 0; k < 4; ++k) {
        if (mode == 1) {
          a0 += fmaxf(bf2f((unsigned short)u[k]) * sc0 + sh0, 0.f);
          a1 += fmaxf(bf2f((unsigned short)(u[k] >> 16)) * sc1 + sh1, 0.f);
        } else {
          a0 += bf2f((unsigned short)u[k]);
          a1 += bf2f((unsigned short)(u[k] >> 16));
        }
      }
      j += 4;
    }
    for (; j < end; ++j) {
      unsigned u = *(const unsigned*)(h + (size_t)csr_col[j] * DIM + ch);
      if (mode == 1) {
        a0 += fmaxf(bf2f((unsigned short)u) * sc0 + sh0, 0.f);
        a1 += fmaxf(bf2f((unsigned short)(u >> 16)) * sc1 + sh1, 0.f);
      } else {
        a0 += bf2f((unsigned short)u);
        a1 += bf2f((unsigned short)(u >> 16));
      }
    }
  } else {
    const float* x = (const float*)src;
    int j = start;
    for (; j + 7 < end; j += 8) {
      int ix[8];
#pragma unroll
      for (int k = 0; k < 8; ++k) ix[k] = csr_col[j + k];
#pragma unroll
      for (int k = 0; k < 8; ++k) {
        float2 v = *(const float2*)(x + (size_t)ix[k] * DIM + ch);
        a0 += v.x; a1 += v.y;
      }
    }
    for (; j < end; ++j) {
      float2 v = *(const float2*)(x + (size_t)csr_col[j] * DIM + ch);
      a0 += v.x; a1 += v.y;
    }
  }
  unsigned o = (unsigned)f2bf(a0) | ((unsigned)f2bf(a1) << 16);
  *(unsigned*)(agg + (size_t)node * DIM + ch) = o;
}

// ================= MFMA GEMM (+BN transform in, +slotted stats out) ======
__global__ __launch_bounds__(256) void gemm_kernel(
    const void* __restrict__ Ap, const unsigned short* __restrict__ agg,
    const unsigned short* __restrict__ PWm, const float* __restrict__ bias,
    const float* __restrict__ stats_in, const float* __restrict__ gv,
    const float* __restrict__ bev, void* __restrict__ Cp,
    float* __restrict__ stats_out, const int* __restrict__ flagp,
    int a_ext, int add_agg, int out_ext) {
  __shared__ unsigned short As[64 * 136];
  __shared__ float red_s[256];
  __shared__ float red_q[256];
  __shared__ float ssl[256];
  const int tid = threadIdx.x;
  const int row0 = blockIdx.x * 64;
  const int bf = *flagp;
  const int has_tf = (stats_in != nullptr);

  if (has_tf) {
    if (tid < 128) {
      float s = 0.f, q = 0.f;
#pragma unroll
      for (int k = 0; k < NSLOT; ++k) {
        s += stats_in[k * 256 + tid];
        q += stats_in[k * 256 + 128 + tid];
      }
      const float invN = 1.0f / (float)N_NODES;
      float m = s * invN;
      float v = q * invN - m * m;
      float scv = gv[tid] * rsqrtf(v + BN_EPS);
      ssl[tid] = scv;
      ssl[128 + tid] = bev[tid] - m * scv;
    }
    __syncthreads();
  }

  for (int i = 0; i < 8; ++i) {
    int G = tid + i * 256;
    int lrow = G >> 5;
    int ch = (G & 31) * 4;
    int grow = row0 + lrow;
    float4 v = make_float4(0.f, 0.f, 0.f, 0.f);
    if (grow < N_NODES) {
      if (a_ext && !bf) {
        v = *(const float4*)((const float*)Ap + (size_t)grow * DIM + ch);
      } else {
        ushort4 u = *(const ushort4*)((const unsigned short*)Ap +
                                      (size_t)grow * DIM + ch);
        v = make_float4(bf2f(u.x), bf2f(u.y), bf2f(u.z), bf2f(u.w));
      }
      if (has_tf) {
        float4 sc = *(const float4*)&ssl[ch];
        float4 sh = *(const float4*)&ssl[128 + ch];
        v.x = fmaxf(v.x * sc.x + sh.x, 0.f);
        v.y = fmaxf(v.y * sc.y + sh.y, 0.f);
        v.z = fmaxf(v.z * sc.z + sh.z, 0.f);
        v.w = fmaxf(v.w * sc.w + sh.w, 0.f);
      }
      if (add_agg) {
        ushort4 au = *(const ushort4*)(agg + (size_t)grow * DIM + ch);
        v.x += bf2f(au.x); v.y += bf2f(au.y);
        v.z += bf2f(au.z); v.w += bf2f(au.w);
      }
    }
    ushort4 o;
    o.x = f2bf(v.x); o.y = f2bf(v.y); o.z = f2bf(v.z); o.w = f2bf(v.w);
    *(ushort4*)&As[lrow * 136 + ch] = o;
  }
  __syncthreads();

  const int wv = tid >> 6, lane = tid & 63;
  const int quad = lane >> 4, lo = lane & 15;
  accf4 acc[8];
#pragma unroll
  for (int nt = 0; nt < 8; ++nt) {
    acc[nt][0] = 0.f; acc[nt][1] = 0.f; acc[nt][2] = 0.f; acc[nt][3] = 0.f;
  }
#pragma unroll
  for (int kt = 0; kt < 4; ++kt) {
    bfrag8 a = *(const bfrag8*)&As[(wv * 16 + lo) * 136 + kt * 32 + quad * 8];
    const unsigned short* pw = PWm + kt * 4096 + lane * 8;
#pragma unroll
    for (int nt = 0; nt < 8; ++nt) {
      bfrag8 b = *(const bfrag8*)(pw + nt * 512);
      acc[nt] = __builtin_amdgcn_mfma_f32_16x16x32_bf16(a, b, acc[nt], 0, 0, 0);
    }
  }
  __syncthreads();

  if (out_ext && !bf) {
    float* Co = (float*)Cp;
#pragma unroll
    for (int nt = 0; nt < 8; ++nt) {
      float b = bias[nt * 16 + lo];
#pragma unroll
      for (int reg = 0; reg < 4; ++reg) {
        int grow = row0 + wv * 16 + quad * 4 + reg;
        if (grow < N_NODES)
          Co[(size_t)grow * DIM + nt * 16 + lo] = acc[nt][reg] + b;
      }
    }
  } else {
#pragma unroll
    for (int nt = 0; nt < 8; ++nt) {
      float b = bias[nt * 16 + lo];
#pragma unroll
      for (int reg = 0; reg < 4; ++reg) {
        As[(wv * 16 + quad * 4 + reg) * 136 + nt * 16 + lo] =
            f2bf(acc[nt][reg] + b);
      }
    }
    __syncthreads();
    unsigned short* Co = (unsigned short*)Cp;
    for (int i = 0; i < 8; ++i) {
      int G = tid + i * 256;
      int lrow = G >> 5, ch = (G & 31) * 4;
      int grow = row0 + lrow;
      if (grow < N_NODES)
        *(ushort4*)(Co + (size_t)grow * DIM + ch) =
            *(const ushort4*)&As[lrow * 136 + ch];
    }
    if (stats_out) {
      int c = tid & 127, rh = tid >> 7;
      int rmax = N_NODES - row0;
      if (rmax > 64) rmax = 64;
      int rend = rh * 32 + 32;
      if (rend > rmax) rend = rmax;
      float s = 0.f, q = 0.f;
      for (int r = rh * 32; r < rend; ++r) {
        float v = bf2f(As[r * 136 + c]);
        s += v; q += v * v;
      }
      red_s[tid] = s; red_q[tid] = q;
      __syncthreads();
      if (tid < 128) {
        float* so = stats_out + (size_t)(blockIdx.x & (NSLOT - 1)) * 256;
        atomicAdd(so + tid, red_s[tid] + red_s[tid + 128]);
        atomicAdd(so + 128 + tid, red_q[tid] + red_q[tid + 128]);
      }
    }
  }
}

extern "C" void kernel_launch(void* const* d_in, const int* in_sizes, int n_in,
                              void* d_out, int out_size, void* d_ws, size_t ws_size,
                              hipStream_t stream) {
  const void* x  = d_in[0];
  const int* row = (const int*)d_in[1];
  const int* col = (const int*)d_in[2];

  const size_t ND = (size_t)N_NODES * DIM;
  unsigned short* agg = (unsigned short*)d_ws;        // ND bf16
  unsigned short* hA  = agg + ND;                     // ND bf16
  unsigned short* hB  = hA + ND;                      // ND bf16
  unsigned short* PW  = hB + ND;                      // 4*16384 bf16
  float* PV    = (float*)(PW + 4 * 16384);            // 10*128 fp32
  float* ps2   = PV + 10 * DIM;                       // 3*NSLOT*256 fp32
  int*   flag  = (int*)(ps2 + 3 * NSLOT * 256);       // 1 (+pad)
  int*   deg   = flag + 4;                            // N
  int*   bcnt  = deg + N_NODES;                       // NBUCK   (contiguous
  int*   gcur  = bcnt + NBUCK;                        // NBUCK    zero range)
  int*   offs  = gcur + NBUCK;                        // N+1
  int*   csr_col = offs + N_NODES + 1;                // E
  unsigned* ebuf = (unsigned*)(csr_col + N_EDGES);    // NBUCK*BCAP u32

  float* S0 = ps2 + 0 * NSLOT * 256;
  float* S1 = ps2 + 1 * NSLOT * 256;
  float* S2 = ps2 + 2 * NSLOT * 256;

  float* c0_b1f = PV + 0 * DIM; float* c0_gf  = PV + 1 * DIM;
  float* c0_bef = PV + 2 * DIM; float* c0_b2f = PV + 3 * DIM;
  float* bn0_gf = PV + 4 * DIM; float* bn0_bef= PV + 5 * DIM;
  float* c1_b1f = PV + 6 * DIM; float* c1_gf  = PV + 7 * DIM;
  float* c1_bef = PV + 8 * DIM; float* c1_b2f = PV + 9 * DIM;

  const int grow_grid = (N_NODES + 3) / 4;  // 12500

  PPtrs pp;
  pp.xs = x;
  pp.w[0] = d_in[3];  pp.w[1] = d_in[7];  pp.w[2] = d_in[11]; pp.w[3] = d_in[15];
  pp.v[0] = d_in[4];  pp.v[1] = d_in[5];  pp.v[2] = d_in[6];  pp.v[3] = d_in[8];
  pp.v[4] = d_in[9];  pp.v[5] = d_in[10]; pp.v[6] = d_in[12]; pp.v[7] = d_in[13];
  pp.v[8] = d_in[14]; pp.v[9] = d_in[16];

  // prep: detect + weights + vectors + flag + zero(ps2, deg, bcnt, gcur)
  prep_kernel<<<40, 256, 0, stream>>>(pp, PW, PV, flag, ps2, deg);

  // CSR build (2 dispatches, write-combined scatter)
  binA_kernel<<<BINA_BLOCKS, 256, 0, stream>>>(row, col, deg, bcnt, gcur, ebuf);
  binB_kernel<<<NBUCK, 256, 0, stream>>>(deg, bcnt, ebuf, csr_col, offs);

  // ---- conv0 ----
  gather_row_kernel<<<grow_grid, 256, 0, stream>>>(
      x, offs, csr_col, nullptr, nullptr, nullptr, agg, flag, 0);
  gemm_kernel<<<GEMM_GRID, 256, 0, stream>>>(
      x, agg, PW + 0 * 16384, c0_b1f, nullptr, nullptr, nullptr,
      hA, S0, flag, 1, 1, 0);
  gemm_kernel<<<GEMM_GRID, 256, 0, stream>>>(
      hA, nullptr, PW + 1 * 16384, c0_b2f, S0, c0_gf, c0_bef,
      hB, S1, flag, 0, 0, 0);

  // ---- conv1 ----
  gather_row_kernel<<<grow_grid, 256, 0, stream>>>(
      hB, offs, csr_col, S1, bn0_gf, bn0_bef, agg, flag, 1);
  gemm_kernel<<<GEMM_GRID, 256, 0, stream>>>(
      hB, agg, PW + 2 * 16384, c1_b1f, S1, bn0_gf, bn0_bef,
      hA, S2, flag, 0, 1, 0);
  gemm_kernel<<<GEMM_GRID, 256, 0, stream>>>(
      hA, nullptr, PW + 3 * 16384, c1_b2f, S2, c1_gf, c1_bef,
      d_out, nullptr, flag, 0, 0, 1);
}

// Round 9
// 304.658 us; speedup vs baseline: 1.2627x; 1.1449x over previous
//
#include <hip/hip_runtime.h>

// GIN 2-layer forward, MI355X (gfx950). Round 20 (= round 19 resubmitted;
// previous bench died with an infra-level "container failed twice", no
// kernel signal. Audit found no hang/OOB path: no spins, 54KB LDS < 64KB
// static limit, dstg bounded by bk*BCAP+gb+h, BCAP=4096 is 17sigma).
//  - binA: per-block LDS counting sort by bucket, then FLAT coalesced
//    write (consecutive lanes -> consecutive ebuf addresses per run).
//  - deg[] global atomics eliminated (binB recomputes counts in LDS).
//  - edges packed u32; prep 5 blocks; gather/gemm proven forms.

#define N_NODES 50000
#define N_EDGES 800000
#define DIM 128
#define BN_EPS 1e-5f
#define GEMM_GRID 782           // ceil(N_NODES/64)
#define NBUCK 256
#define NPB 196                 // nodes per bucket
#define BCAP 4096               // max edges per bucket (mean 3136, 17 sigma)
#define BINA_BLOCKS 128
#define EPB 6250                // 128 * 6250 = 800000 exact
#define NSLOT 16                // stats atomic slots

using bfrag8 = __attribute__((ext_vector_type(8))) short;
using accf4  = __attribute__((ext_vector_type(4))) float;

__device__ __forceinline__ float bf2f(unsigned short u) {
  union { unsigned u32; float f; } c;
  c.u32 = ((unsigned)u) << 16;
  return c.f;
}
__device__ __forceinline__ unsigned short f2bf(float f) {
  union { float f; unsigned u32; } c;
  c.f = f;
  unsigned u = c.u32;
  return (unsigned short)((u + 0x7fffu + ((u >> 16) & 1u)) >> 16);  // RNE
}

// ---- prep: detect dtype, pack weights, convert vectors, zero scratch ----
struct PPtrs { const void* xs; const void* w[4]; const void* v[10]; };

__global__ __launch_bounds__(256) void prep_kernel(
    PPtrs pp, unsigned short* __restrict__ PW, float* __restrict__ PV,
    int* __restrict__ flag, float* __restrict__ ps2, int* __restrict__ bcg) {
  __shared__ int oks[64];
  __shared__ int bfs;
  int t = threadIdx.x;
  if (t < 64) {
    unsigned short u = ((const unsigned short*)pp.xs)[t * 2];
    int e = (u >> 7) & 0xFF;
    oks[t] = ((e >= 96 && e <= 134) || ((u & 0x7FFFu) == 0)) ? 1 : 0;
  }
  __syncthreads();
  if (t == 0) {
    int c = 0;
    for (int i = 0; i < 64; ++i) c += oks[i];
    bfs = (c >= 56) ? 1 : 0;
  }
  __syncthreads();
  int bf = bfs;
  int b = blockIdx.x;

  if (b < 4) {
    const void* src = pp.w[b];
    unsigned short* dst = PW + (size_t)b * 16384;
    for (int f = t; f < 2048; f += 256) {
      int kt = f >> 9, nt = (f >> 6) & 7, lane = f & 63;
      int kbase = kt * 32 + (lane >> 4) * 8;
      int n = nt * 16 + (lane & 15);
      unsigned short tmp[8];
      for (int j = 0; j < 8; ++j) {
        int idx = (kbase + j) * DIM + n;
        if (bf) tmp[j] = ((const unsigned short*)src)[idx];
        else    tmp[j] = f2bf(((const float*)src)[idx]);
      }
      for (int j = 0; j < 8; ++j) dst[f * 8 + j] = tmp[j];
    }
  } else {
    for (int j = t; j < 10 * DIM; j += 256) {
      int vec = j >> 7, idx = j & 127;
      float v;
      if (bf) v = bf2f(((const unsigned short*)pp.v[vec])[idx]);
      else    v = ((const float*)pp.v[vec])[idx];
      PV[j] = v;
    }
    if (t == 0) *flag = bf;
    for (int j = t; j < 3 * NSLOT * 256; j += 256) ps2[j] = 0.f;
    for (int j = t; j < 2 * NBUCK; j += 256) bcg[j] = 0;
  }
}

// ================= CSR build =================
// binA: LDS counting-sort of the block's 6250 edges by bucket, then flat
// coalesced write. seg[s] holds packed (r | c<<16), dstg[s] the absolute
// ebuf index; consecutive s within a bucket run -> consecutive dstg.
__global__ __launch_bounds__(256) void binA_kernel(
    const int* __restrict__ row, const int* __restrict__ col,
    int* __restrict__ bcnt, int* __restrict__ gcur,
    unsigned* __restrict__ ebuf) {
  __shared__ int hist[NBUCK];
  __shared__ int lofs[NBUCK];
  __shared__ int gbase[NBUCK];
  __shared__ int cur[NBUCK];
  __shared__ unsigned seg[EPB];
  __shared__ int dstg[EPB];
  int t = threadIdx.x;
  int e0 = blockIdx.x * EPB;

  hist[t] = 0;
  __syncthreads();
  for (int i = t; i < EPB; i += 256)
    atomicAdd(&hist[row[e0 + i] / NPB], 1);
  __syncthreads();
  int h = hist[t];
  lofs[t] = h;
  __syncthreads();
  for (int d = 1; d < 256; d <<= 1) {
    int v = (t >= d) ? lofs[t - d] : 0;
    __syncthreads();
    lofs[t] += v;
    __syncthreads();
  }
  int excl = lofs[t] - h;
  int gb = h ? atomicAdd(&gcur[t], h) : 0;
  if (h) atomicAdd(&bcnt[t], h);
  __syncthreads();
  lofs[t] = excl;
  cur[t] = excl;
  gbase[t] = t * BCAP + gb;      // absolute segment base for this run
  __syncthreads();
  for (int i = t; i < EPB; i += 256) {
    int r = row[e0 + i];
    int c = col[e0 + i];
    int bk = r / NPB;
    int s = atomicAdd(&cur[bk], 1);
    seg[s] = (unsigned)r | ((unsigned)c << 16);
    dstg[s] = gbase[bk] + (s - lofs[bk]);
  }
  __syncthreads();
  for (int s = t; s < EPB; s += 256)
    ebuf[dstg[s]] = seg[s];
}

// binB: redundant bcnt scan -> segbase; per-node counts recomputed from
// the bucket segment (no global deg); local scan -> offs; LDS counting
// sort by node; sequential csr_col write.
__global__ __launch_bounds__(256) void binB_kernel(
    const int* __restrict__ bcnt, const unsigned* __restrict__ ebuf,
    int* __restrict__ csr_col, int* __restrict__ offs) {
  __shared__ int sc[256];
  __shared__ int dg[256];
  __shared__ int cur[NPB];
  __shared__ int seg[BCAP];
  int b = blockIdx.x;
  int t = threadIdx.x;

  sc[t] = bcnt[t];
  __syncthreads();
  for (int d = 1; d < 256; d <<= 1) {
    int v = (t >= d) ? sc[t - d] : 0;
    __syncthreads();
    sc[t] += v;
    __syncthreads();
  }
  int segbase = (b == 0) ? 0 : sc[b - 1];

  int nb = b * NPB;
  int nend = nb + NPB;
  if (nend > N_NODES) nend = N_NODES;
  int nn = nend - nb;
  int cnt = bcnt[b];
  const unsigned* eb = ebuf + (size_t)b * BCAP;

  if (t < NPB) cur[t] = 0;
  __syncthreads();
  // pass1: per-node counts from the segment
  for (int i = t; i < cnt; i += 256) {
    int r = (int)(eb[i] & 0xFFFFu);
    atomicAdd(&cur[r - nb], 1);
  }
  __syncthreads();
  int myd = (t < nn) ? cur[t] : 0;
  dg[t] = myd;
  __syncthreads();
  for (int d = 1; d < 256; d <<= 1) {
    int v = (t >= d) ? dg[t - d] : 0;
    __syncthreads();
    dg[t] += v;
    __syncthreads();
  }
  int excl = dg[t] - myd;
  if (t < nn) {
    offs[nb + t] = segbase + excl;
    cur[t] = excl;
  }
  if (b == NBUCK - 1 && t == 0) offs[N_NODES] = N_EDGES;
  __syncthreads();
  // pass2: counting sort by node
  for (int i = t; i < cnt; i += 256) {
    unsigned e = eb[i];
    int r = (int)(e & 0xFFFFu);
    int slot = atomicAdd(&cur[r - nb], 1);
    seg[slot] = (int)(e >> 16);
  }
  __syncthreads();
  for (int i = t; i < cnt; i += 256)
    csr_col[segbase + i] = seg[i];
}

// ================= full-row gather, unroll-16 (proven 56us form) =========
__global__ __launch_bounds__(256, 4) void gather_row_kernel(
    const void* __restrict__ src, const int* __restrict__ offs,
    const int* __restrict__ csr_col, const float* __restrict__ stats_in,
    const float* __restrict__ gv, const float* __restrict__ bev,
    unsigned short* __restrict__ agg, const int* __restrict__ flagp,
    int mode) {
  __shared__ float ssl[256];
  int tid = threadIdx.x;
  if (mode == 1) {
    if (tid < 128) {
      float s = 0.f, q = 0.f;
#pragma unroll
      for (int k = 0; k < NSLOT; ++k) {
        s += stats_in[k * 256 + tid];
        q += stats_in[k * 256 + 128 + tid];
      }
      const float invN = 1.0f / (float)N_NODES;
      float m = s * invN;
      float v = q * invN - m * m;
      float scv = gv[tid] * rsqrtf(v + BN_EPS);
      ssl[tid] = scv;
      ssl[128 + tid] = bev[tid] - m * scv;
    }
    __syncthreads();
  }

  int node = blockIdx.x * 4 + (tid >> 6);
  if (node >= N_NODES) return;
  int lane = tid & 63;
  int ch = lane * 2;
  int start = offs[node], end = offs[node + 1];
  float a0 = 0.f, a1 = 0.f;
  int bf = *flagp;
  float sc0 = 0.f, sc1 = 0.f, sh0 = 0.f, sh1 = 0.f;
  if (mode == 1) {
    sc0 = ssl[ch]; sc1 = ssl[ch + 1];
    sh0 = ssl[128 + ch]; sh1 = ssl[128 + ch + 1];
  }

  if (mode == 1 || bf) {
    const unsigned short* h = (const unsigned short*)src;
    int j = start;
    for (; j + 15 < end; j += 16) {
      int ix[16];
#pragma unroll
      for (int k = 0; k < 16; ++k) ix[k] = csr_col[j + k];
      unsigned u[16];
#pragma unroll
      for (int k = 0; k < 16; ++k)
        u[k] = *(const unsigned*)(h + (size_t)ix[k] * DIM + ch);
      if (mode == 1) {
#pragma unroll
        for (int k = 0; k < 16; ++k) {
          a0 += fmaxf(bf2f((unsigned short)u[k]) * sc0 + sh0, 0.f);
          a1 += fmaxf(bf2f((unsigned short)(u[k] >> 16)) * sc1 + sh1, 0.f);
        }
      } else {
#pragma unroll
        for (int k = 0; k < 16; ++k) {
          a0 += bf2f((unsigned short)u[k]);
          a1 += bf2f((unsigned short)(u[k] >> 16));
        }
      }
    }
    if (j + 7 < end) {
      int ix[8];
#pragma unroll
      for (int k = 0; k < 8; ++k) ix[k] = csr_col[j + k];
      unsigned u[8];
#pragma unroll
      for (int k = 0; k < 8; ++k)
        u[k] = *(const unsigned*)(h + (size_t)ix[k] * DIM + ch);
#pragma unroll
      for (int k = 0; k < 8; ++k) {
        if (mode == 1) {
          a0 += fmaxf(bf2f((unsigned short)u[k]) * sc0 + sh0, 0.f);
          a1 += fmaxf(bf2f((unsigned short)(u[k] >> 16)) * sc1 + sh1, 0.f);
        } else {
          a0 += bf2f((unsigned short)u[k]);
          a1 += bf2f((unsigned short)(u[k] >> 16));
        }
      }
      j += 8;
    }
    if (j + 3 < end) {
      int ix[4];
#pragma unroll
      for (int k = 0; k < 4; ++k) ix[k] = csr_col[j + k];
      unsigned u[4];
#pragma unroll
      for (int k = 0; k < 4; ++k)
        u[k] = *(const unsigned*)(h + (size_t)ix[k] * DIM + ch);
#pragma unroll
      for (int k = 0; k < 4; ++k) {
        if (mode == 1) {
          a0 += fmaxf(bf2f((unsigned short)u[k]) * sc0 + sh0, 0.f);
          a1 += fmaxf(bf2f((unsigned short)(u[k] >> 16)) * sc1 + sh1, 0.f);
        } else {
          a0 += bf2f((unsigned short)u[k]);
          a1 += bf2f((unsigned short)(u[k] >> 16));
        }
      }
      j += 4;
    }
    for (; j < end; ++j) {
      unsigned u = *(const unsigned*)(h + (size_t)csr_col[j] * DIM + ch);
      if (mode == 1) {
        a0 += fmaxf(bf2f((unsigned short)u) * sc0 + sh0, 0.f);
        a1 += fmaxf(bf2f((unsigned short)(u >> 16)) * sc1 + sh1, 0.f);
      } else {
        a0 += bf2f((unsigned short)u);
        a1 += bf2f((unsigned short)(u >> 16));
      }
    }
  } else {
    const float* x = (const float*)src;
    int j = start;
    for (; j + 7 < end; j += 8) {
      int ix[8];
#pragma unroll
      for (int k = 0; k < 8; ++k) ix[k] = csr_col[j + k];
#pragma unroll
      for (int k = 0; k < 8; ++k) {
        float2 v = *(const float2*)(x + (size_t)ix[k] * DIM + ch);
        a0 += v.x; a1 += v.y;
      }
    }
    for (; j < end; ++j) {
      float2 v = *(const float2*)(x + (size_t)csr_col[j] * DIM + ch);
      a0 += v.x; a1 += v.y;
    }
  }
  unsigned o = (unsigned)f2bf(a0) | ((unsigned)f2bf(a1) << 16);
  *(unsigned*)(agg + (size_t)node * DIM + ch) = o;
}

// ================= MFMA GEMM (+BN transform in, +slotted stats out) ======
__global__ __launch_bounds__(256) void gemm_kernel(
    const void* __restrict__ Ap, const unsigned short* __restrict__ agg,
    const unsigned short* __restrict__ PWm, const float* __restrict__ bias,
    const float* __restrict__ stats_in, const float* __restrict__ gv,
    const float* __restrict__ bev, void* __restrict__ Cp,
    float* __restrict__ stats_out, const int* __restrict__ flagp,
    int a_ext, int add_agg, int out_ext) {
  __shared__ unsigned short As[64 * 136];
  __shared__ float red_s[256];
  __shared__ float red_q[256];
  __shared__ float ssl[256];
  const int tid = threadIdx.x;
  const int row0 = blockIdx.x * 64;
  const int bf = *flagp;
  const int has_tf = (stats_in != nullptr);

  if (has_tf) {
    if (tid < 128) {
      float s = 0.f, q = 0.f;
#pragma unroll
      for (int k = 0; k < NSLOT; ++k) {
        s += stats_in[k * 256 + tid];
        q += stats_in[k * 256 + 128 + tid];
      }
      const float invN = 1.0f / (float)N_NODES;
      float m = s * invN;
      float v = q * invN - m * m;
      float scv = gv[tid] * rsqrtf(v + BN_EPS);
      ssl[tid] = scv;
      ssl[128 + tid] = bev[tid] - m * scv;
    }
    __syncthreads();
  }

  for (int i = 0; i < 8; ++i) {
    int G = tid + i * 256;
    int lrow = G >> 5;
    int ch = (G & 31) * 4;
    int grow = row0 + lrow;
    float4 v = make_float4(0.f, 0.f, 0.f, 0.f);
    if (grow < N_NODES) {
      if (a_ext && !bf) {
        v = *(const float4*)((const float*)Ap + (size_t)grow * DIM + ch);
      } else {
        ushort4 u = *(const ushort4*)((const unsigned short*)Ap +
                                      (size_t)grow * DIM + ch);
        v = make_float4(bf2f(u.x), bf2f(u.y), bf2f(u.z), bf2f(u.w));
      }
      if (has_tf) {
        float4 sc = *(const float4*)&ssl[ch];
        float4 sh = *(const float4*)&ssl[128 + ch];
        v.x = fmaxf(v.x * sc.x + sh.x, 0.f);
        v.y = fmaxf(v.y * sc.y + sh.y, 0.f);
        v.z = fmaxf(v.z * sc.z + sh.z, 0.f);
        v.w = fmaxf(v.w * sc.w + sh.w, 0.f);
      }
      if (add_agg) {
        ushort4 au = *(const ushort4*)(agg + (size_t)grow * DIM + ch);
        v.x += bf2f(au.x); v.y += bf2f(au.y);
        v.z += bf2f(au.z); v.w += bf2f(au.w);
      }
    }
    ushort4 o;
    o.x = f2bf(v.x); o.y = f2bf(v.y); o.z = f2bf(v.z); o.w = f2bf(v.w);
    *(ushort4*)&As[lrow * 136 + ch] = o;
  }
  __syncthreads();

  const int wv = tid >> 6, lane = tid & 63;
  const int quad = lane >> 4, lo = lane & 15;
  accf4 acc[8];
#pragma unroll
  for (int nt = 0; nt < 8; ++nt) {
    acc[nt][0] = 0.f; acc[nt][1] = 0.f; acc[nt][2] = 0.f; acc[nt][3] = 0.f;
  }
#pragma unroll
  for (int kt = 0; kt < 4; ++kt) {
    bfrag8 a = *(const bfrag8*)&As[(wv * 16 + lo) * 136 + kt * 32 + quad * 8];
    const unsigned short* pw = PWm + kt * 4096 + lane * 8;
#pragma unroll
    for (int nt = 0; nt < 8; ++nt) {
      bfrag8 b = *(const bfrag8*)(pw + nt * 512);
      acc[nt] = __builtin_amdgcn_mfma_f32_16x16x32_bf16(a, b, acc[nt], 0, 0, 0);
    }
  }
  __syncthreads();

  if (out_ext && !bf) {
    float* Co = (float*)Cp;
#pragma unroll
    for (int nt = 0; nt < 8; ++nt) {
      float b = bias[nt * 16 + lo];
#pragma unroll
      for (int reg = 0; reg < 4; ++reg) {
        int grow = row0 + wv * 16 + quad * 4 + reg;
        if (grow < N_NODES)
          Co[(size_t)grow * DIM + nt * 16 + lo] = acc[nt][reg] + b;
      }
    }
  } else {
#pragma unroll
    for (int nt = 0; nt < 8; ++nt) {
      float b = bias[nt * 16 + lo];
#pragma unroll
      for (int reg = 0; reg < 4; ++reg) {
        As[(wv * 16 + quad * 4 + reg) * 136 + nt * 16 + lo] =
            f2bf(acc[nt][reg] + b);
      }
    }
    __syncthreads();
    unsigned short* Co = (unsigned short*)Cp;
    for (int i = 0; i < 8; ++i) {
      int G = tid + i * 256;
      int lrow = G >> 5, ch = (G & 31) * 4;
      int grow = row0 + lrow;
      if (grow < N_NODES)
        *(ushort4*)(Co + (size_t)grow * DIM + ch) =
            *(const ushort4*)&As[lrow * 136 + ch];
    }
    if (stats_out) {
      int c = tid & 127, rh = tid >> 7;
      int rmax = N_NODES - row0;
      if (rmax > 64) rmax = 64;
      int rend = rh * 32 + 32;
      if (rend > rmax) rend = rmax;
      float s = 0.f, q = 0.f;
      for (int r = rh * 32; r < rend; ++r) {
        float v = bf2f(As[r * 136 + c]);
        s += v; q += v * v;
      }
      red_s[tid] = s; red_q[tid] = q;
      __syncthreads();
      if (tid < 128) {
        float* so = stats_out + (size_t)(blockIdx.x & (NSLOT - 1)) * 256;
        atomicAdd(so + tid, red_s[tid] + red_s[tid + 128]);
        atomicAdd(so + 128 + tid, red_q[tid] + red_q[tid + 128]);
      }
    }
  }
}

extern "C" void kernel_launch(void* const* d_in, const int* in_sizes, int n_in,
                              void* d_out, int out_size, void* d_ws, size_t ws_size,
                              hipStream_t stream) {
  const void* x  = d_in[0];
  const int* row = (const int*)d_in[1];
  const int* col = (const int*)d_in[2];

  const size_t ND = (size_t)N_NODES * DIM;
  unsigned short* agg = (unsigned short*)d_ws;        // ND bf16
  unsigned short* hA  = agg + ND;                     // ND bf16
  unsigned short* hB  = hA + ND;                      // ND bf16
  unsigned short* PW  = hB + ND;                      // 4*16384 bf16
  float* PV    = (float*)(PW + 4 * 16384);            // 10*128 fp32
  float* ps2   = PV + 10 * DIM;                       // 3*NSLOT*256 fp32
  int*   flag  = (int*)(ps2 + 3 * NSLOT * 256);       // 1 (+pad)
  int*   bcnt  = flag + 4;                            // NBUCK   (contiguous
  int*   gcur  = bcnt + NBUCK;                        // NBUCK    zero range)
  int*   offs  = gcur + NBUCK;                        // N+1
  int*   csr_col = offs + N_NODES + 1;                // E
  unsigned* ebuf = (unsigned*)(csr_col + N_EDGES);    // NBUCK*BCAP u32

  float* S0 = ps2 + 0 * NSLOT * 256;
  float* S1 = ps2 + 1 * NSLOT * 256;
  float* S2 = ps2 + 2 * NSLOT * 256;

  float* c0_b1f = PV + 0 * DIM; float* c0_gf  = PV + 1 * DIM;
  float* c0_bef = PV + 2 * DIM; float* c0_b2f = PV + 3 * DIM;
  float* bn0_gf = PV + 4 * DIM; float* bn0_bef= PV + 5 * DIM;
  float* c1_b1f = PV + 6 * DIM; float* c1_gf  = PV + 7 * DIM;
  float* c1_bef = PV + 8 * DIM; float* c1_b2f = PV + 9 * DIM;

  const int grow_grid = (N_NODES + 3) / 4;  // 12500

  PPtrs pp;
  pp.xs = x;
  pp.w[0] = d_in[3];  pp.w[1] = d_in[7];  pp.w[2] = d_in[11]; pp.w[3] = d_in[15];
  pp.v[0] = d_in[4];  pp.v[1] = d_in[5];  pp.v[2] = d_in[6];  pp.v[3] = d_in[8];
  pp.v[4] = d_in[9];  pp.v[5] = d_in[10]; pp.v[6] = d_in[12]; pp.v[7] = d_in[13];
  pp.v[8] = d_in[14]; pp.v[9] = d_in[16];

  // prep: detect + weights + vectors + flag + zero(ps2, bcnt, gcur)
  prep_kernel<<<5, 256, 0, stream>>>(pp, PW, PV, flag, ps2, bcnt);

  // CSR build (2 dispatches, locally-sorted coalesced scatter)
  binA_kernel<<<BINA_BLOCKS, 256, 0, stream>>>(row, col, bcnt, gcur, ebuf);
  binB_kernel<<<NBUCK, 256, 0, stream>>>(bcnt, ebuf, csr_col, offs);

  // ---- conv0 ----
  gather_row_kernel<<<grow_grid, 256, 0, stream>>>(
      x, offs, csr_col, nullptr, nullptr, nullptr, agg, flag, 0);
  gemm_kernel<<<GEMM_GRID, 256, 0, stream>>>(
      x, agg, PW + 0 * 16384, c0_b1f, nullptr, nullptr, nullptr,
      hA, S0, flag, 1, 1, 0);
  gemm_kernel<<<GEMM_GRID, 256, 0, stream>>>(
      hA, nullptr, PW + 1 * 16384, c0_b2f, S0, c0_gf, c0_bef,
      hB, S1, flag, 0, 0, 0);

  // ---- conv1 ----
  gather_row_kernel<<<grow_grid, 256, 0, stream>>>(
      hB, offs, csr_col, S1, bn0_gf, bn0_bef, agg, flag, 1);
  gemm_kernel<<<GEMM_GRID, 256, 0, stream>>>(
      hB, agg, PW + 2 * 16384, c1_b1f, S1, bn0_gf, bn0_bef,
      hA, S2, flag, 0, 1, 0);
  gemm_kernel<<<GEMM_GRID, 256, 0, stream>>>(
      hA, nullptr, PW + 3 * 16384, c1_b2f, S2, c1_gf, c1_bef,
      d_out, nullptr, flag, 0, 0, 1);
}

// Round 10
// 274.680 us; speedup vs baseline: 1.4005x; 1.1091x over previous
//
#include <hip/hip_runtime.h>

// GIN 2-layer forward, MI355X (gfx950). Round 21: mid-tier consolidation.
//  - prep MERGED into binA (independent work): blocks 0..127 bin edges,
//    128..159 pack weights (8 blocks/matrix -> ~8x packing parallelism),
//    160 converts vectors + flag + zeroes ps2. bcnt/gcur zeroing via 2KB
//    hipMemsetAsync. Removes prep's serialized ~20us + 1 dispatch gap.
//  - GEMM stage + C-write loops widened to 16B/lane (ushort8): 8 -> 4
//    iterations, half the memory instructions per GEMM prologue/epilogue.
//  - CSR scatter (r20 proven: lane-consecutive coalesced), gather (r15
//    proven 3.4TB/s structural ceiling) unchanged.

#define N_NODES 50000
#define N_EDGES 800000
#define DIM 128
#define BN_EPS 1e-5f
#define GEMM_GRID 782           // ceil(N_NODES/64)
#define NBUCK 256
#define NPB 196                 // nodes per bucket
#define BCAP 4096               // max edges per bucket (mean 3136, 17 sigma)
#define BINA_BLOCKS 128
#define EPB 6250                // 128 * 6250 = 800000 exact
#define NSLOT 16                // stats atomic slots

using bfrag8 = __attribute__((ext_vector_type(8))) short;
using accf4  = __attribute__((ext_vector_type(4))) float;
using u16x8  = __attribute__((ext_vector_type(8))) unsigned short;

__device__ __forceinline__ float bf2f(unsigned short u) {
  union { unsigned u32; float f; } c;
  c.u32 = ((unsigned)u) << 16;
  return c.f;
}
__device__ __forceinline__ unsigned short f2bf(float f) {
  union { float f; unsigned u32; } c;
  c.f = f;
  unsigned u = c.u32;
  return (unsigned short)((u + 0x7fffu + ((u >> 16) & 1u)) >> 16);  // RNE
}

struct PPtrs { const void* xs; const void* w[4]; const void* v[10]; };

// ================= binA + prep (merged) =================
// blocks 0..127: LDS counting-sort of 6250 edges by bucket -> flat
//   coalesced ebuf write (lane-consecutive within each bucket run).
// blocks 128..159: weight packing, 8 blocks per matrix (1 frag/thread).
// block 160: vectors + flag + ps2 zeroing.
__global__ __launch_bounds__(256) void binA_kernel(
    const int* __restrict__ row, const int* __restrict__ col,
    int* __restrict__ bcnt, int* __restrict__ gcur,
    unsigned* __restrict__ ebuf, PPtrs pp,
    unsigned short* __restrict__ PW, float* __restrict__ PV,
    int* __restrict__ flag, float* __restrict__ ps2) {
  __shared__ int hist[NBUCK];
  __shared__ int lofs[NBUCK];
  __shared__ int gbase[NBUCK];
  __shared__ int cur[NBUCK];
  __shared__ unsigned seg[EPB];
  __shared__ int dstg[EPB];
  int t = threadIdx.x;
  int b = blockIdx.x;

  if (b >= BINA_BLOCKS) {
    // ---- prep path: per-block dtype detection ----
    __shared__ int oks[64];
    __shared__ int bfs;
    if (t < 64) {
      unsigned short u = ((const unsigned short*)pp.xs)[t * 2];
      int e = (u >> 7) & 0xFF;
      oks[t] = ((e >= 96 && e <= 134) || ((u & 0x7FFFu) == 0)) ? 1 : 0;
    }
    __syncthreads();
    if (t == 0) {
      int c = 0;
      for (int i = 0; i < 64; ++i) c += oks[i];
      bfs = (c >= 56) ? 1 : 0;
    }
    __syncthreads();
    int bf = bfs;
    int pb = b - BINA_BLOCKS;
    if (pb < 32) {
      int mat = pb >> 3, part = pb & 7;
      const void* src = pp.w[mat];
      unsigned short* dst = PW + (size_t)mat * 16384;
      int f = part * 256 + t;            // one fragment per thread
      int kt = f >> 9, nt = (f >> 6) & 7, lane = f & 63;
      int kbase = kt * 32 + (lane >> 4) * 8;
      int n = nt * 16 + (lane & 15);
      unsigned short tmp[8];
      for (int j = 0; j < 8; ++j) {
        int idx = (kbase + j) * DIM + n;
        if (bf) tmp[j] = ((const unsigned short*)src)[idx];
        else    tmp[j] = f2bf(((const float*)src)[idx]);
      }
      for (int j = 0; j < 8; ++j) dst[f * 8 + j] = tmp[j];
    } else {
      for (int j = t; j < 10 * DIM; j += 256) {
        int vec = j >> 7, idx = j & 127;
        float v;
        if (bf) v = bf2f(((const unsigned short*)pp.v[vec])[idx]);
        else    v = ((const float*)pp.v[vec])[idx];
        PV[j] = v;
      }
      if (t == 0) *flag = bf;
      for (int j = t; j < 3 * NSLOT * 256; j += 256) ps2[j] = 0.f;
    }
    return;
  }

  // ---- edge-binning path ----
  int e0 = b * EPB;
  hist[t] = 0;
  __syncthreads();
  for (int i = t; i < EPB; i += 256)
    atomicAdd(&hist[row[e0 + i] / NPB], 1);
  __syncthreads();
  int h = hist[t];
  lofs[t] = h;
  __syncthreads();
  for (int d = 1; d < 256; d <<= 1) {
    int v = (t >= d) ? lofs[t - d] : 0;
    __syncthreads();
    lofs[t] += v;
    __syncthreads();
  }
  int excl = lofs[t] - h;
  int gb = h ? atomicAdd(&gcur[t], h) : 0;
  if (h) atomicAdd(&bcnt[t], h);
  __syncthreads();
  lofs[t] = excl;
  cur[t] = excl;
  gbase[t] = t * BCAP + gb;      // absolute segment base for this run
  __syncthreads();
  for (int i = t; i < EPB; i += 256) {
    int r = row[e0 + i];
    int c = col[e0 + i];
    int bk = r / NPB;
    int s = atomicAdd(&cur[bk], 1);
    seg[s] = (unsigned)r | ((unsigned)c << 16);
    dstg[s] = gbase[bk] + (s - lofs[bk]);
  }
  __syncthreads();
  for (int s = t; s < EPB; s += 256)
    ebuf[dstg[s]] = seg[s];
}

// binB: redundant bcnt scan -> segbase; per-node counts recomputed from
// the bucket segment; local scan -> offs; LDS counting sort by node.
__global__ __launch_bounds__(256) void binB_kernel(
    const int* __restrict__ bcnt, const unsigned* __restrict__ ebuf,
    int* __restrict__ csr_col, int* __restrict__ offs) {
  __shared__ int sc[256];
  __shared__ int dg[256];
  __shared__ int cur[NPB];
  __shared__ int seg[BCAP];
  int b = blockIdx.x;
  int t = threadIdx.x;

  sc[t] = bcnt[t];
  __syncthreads();
  for (int d = 1; d < 256; d <<= 1) {
    int v = (t >= d) ? sc[t - d] : 0;
    __syncthreads();
    sc[t] += v;
    __syncthreads();
  }
  int segbase = (b == 0) ? 0 : sc[b - 1];

  int nb = b * NPB;
  int nend = nb + NPB;
  if (nend > N_NODES) nend = N_NODES;
  int nn = nend - nb;
  int cnt = bcnt[b];
  const unsigned* eb = ebuf + (size_t)b * BCAP;

  if (t < NPB) cur[t] = 0;
  __syncthreads();
  for (int i = t; i < cnt; i += 256) {
    int r = (int)(eb[i] & 0xFFFFu);
    atomicAdd(&cur[r - nb], 1);
  }
  __syncthreads();
  int myd = (t < nn) ? cur[t] : 0;
  dg[t] = myd;
  __syncthreads();
  for (int d = 1; d < 256; d <<= 1) {
    int v = (t >= d) ? dg[t - d] : 0;
    __syncthreads();
    dg[t] += v;
    __syncthreads();
  }
  int excl = dg[t] - myd;
  if (t < nn) {
    offs[nb + t] = segbase + excl;
    cur[t] = excl;
  }
  if (b == NBUCK - 1 && t == 0) offs[N_NODES] = N_EDGES;
  __syncthreads();
  for (int i = t; i < cnt; i += 256) {
    unsigned e = eb[i];
    int r = (int)(e & 0xFFFFu);
    int slot = atomicAdd(&cur[r - nb], 1);
    seg[slot] = (int)(e >> 16);
  }
  __syncthreads();
  for (int i = t; i < cnt; i += 256)
    csr_col[segbase + i] = seg[i];
}

// ================= full-row gather, unroll-16 (proven 56us form) =========
__global__ __launch_bounds__(256, 4) void gather_row_kernel(
    const void* __restrict__ src, const int* __restrict__ offs,
    const int* __restrict__ csr_col, const float* __restrict__ stats_in,
    const float* __restrict__ gv, const float* __restrict__ bev,
    unsigned short* __restrict__ agg, const int* __restrict__ flagp,
    int mode) {
  __shared__ float ssl[256];
  int tid = threadIdx.x;
  if (mode == 1) {
    if (tid < 128) {
      float s = 0.f, q = 0.f;
#pragma unroll
      for (int k = 0; k < NSLOT; ++k) {
        s += stats_in[k * 256 + tid];
        q += stats_in[k * 256 + 128 + tid];
      }
      const float invN = 1.0f / (float)N_NODES;
      float m = s * invN;
      float v = q * invN - m * m;
      float scv = gv[tid] * rsqrtf(v + BN_EPS);
      ssl[tid] = scv;
      ssl[128 + tid] = bev[tid] - m * scv;
    }
    __syncthreads();
  }

  int node = blockIdx.x * 4 + (tid >> 6);
  if (node >= N_NODES) return;
  int lane = tid & 63;
  int ch = lane * 2;
  int start = offs[node], end = offs[node + 1];
  float a0 = 0.f, a1 = 0.f;
  int bf = *flagp;
  float sc0 = 0.f, sc1 = 0.f, sh0 = 0.f, sh1 = 0.f;
  if (mode == 1) {
    sc0 = ssl[ch]; sc1 = ssl[ch + 1];
    sh0 = ssl[128 + ch]; sh1 = ssl[128 + ch + 1];
  }

  if (mode == 1 || bf) {
    const unsigned short* h = (const unsigned short*)src;
    int j = start;
    for (; j + 15 < end; j += 16) {
      int ix[16];
#pragma unroll
      for (int k = 0; k < 16; ++k) ix[k] = csr_col[j + k];
      unsigned u[16];
#pragma unroll
      for (int k = 0; k < 16; ++k)
        u[k] = *(const unsigned*)(h + (size_t)ix[k] * DIM + ch);
      if (mode == 1) {
#pragma unroll
        for (int k = 0; k < 16; ++k) {
          a0 += fmaxf(bf2f((unsigned short)u[k]) * sc0 + sh0, 0.f);
          a1 += fmaxf(bf2f((unsigned short)(u[k] >> 16)) * sc1 + sh1, 0.f);
        }
      } else {
#pragma unroll
        for (int k = 0; k < 16; ++k) {
          a0 += bf2f((unsigned short)u[k]);
          a1 += bf2f((unsigned short)(u[k] >> 16));
        }
      }
    }
    if (j + 7 < end) {
      int ix[8];
#pragma unroll
      for (int k = 0; k < 8; ++k) ix[k] = csr_col[j + k];
      unsigned u[8];
#pragma unroll
      for (int k = 0; k < 8; ++k)
        u[k] = *(const unsigned*)(h + (size_t)ix[k] * DIM + ch);
#pragma unroll
      for (int k = 0; k < 8; ++k) {
        if (mode == 1) {
          a0 += fmaxf(bf2f((unsigned short)u[k]) * sc0 + sh0, 0.f);
          a1 += fmaxf(bf2f((unsigned short)(u[k] >> 16)) * sc1 + sh1, 0.f);
        } else {
          a0 += bf2f((unsigned short)u[k]);
          a1 += bf2f((unsigned short)(u[k] >> 16));
        }
      }
      j += 8;
    }
    if (j + 3 < end) {
      int ix[4];
#pragma unroll
      for (int k = 0; k < 4; ++k) ix[k] = csr_col[j + k];
      unsigned u[4];
#pragma unroll
      for (int k = 0; k < 4; ++k)
        u[k] = *(const unsigned*)(h + (size_t)ix[k] * DIM + ch);
#pragma unroll
      for (int k = 0; k < 4; ++k) {
        if (mode == 1) {
          a0 += fmaxf(bf2f((unsigned short)u[k]) * sc0 + sh0, 0.f);
          a1 += fmaxf(bf2f((unsigned short)(u[k] >> 16)) * sc1 + sh1, 0.f);
        } else {
          a0 += bf2f((unsigned short)u[k]);
          a1 += bf2f((unsigned short)(u[k] >> 16));
        }
      }
      j += 4;
    }
    for (; j < end; ++j) {
      unsigned u = *(const unsigned*)(h + (size_t)csr_col[j] * DIM + ch);
      if (mode == 1) {
        a0 += fmaxf(bf2f((unsigned short)u) * sc0 + sh0, 0.f);
        a1 += fmaxf(bf2f((unsigned short)(u >> 16)) * sc1 + sh1, 0.f);
      } else {
        a0 += bf2f((unsigned short)u);
        a1 += bf2f((unsigned short)(u >> 16));
      }
    }
  } else {
    const float* x = (const float*)src;
    int j = start;
    for (; j + 7 < end; j += 8) {
      int ix[8];
#pragma unroll
      for (int k = 0; k < 8; ++k) ix[k] = csr_col[j + k];
#pragma unroll
      for (int k = 0; k < 8; ++k) {
        float2 v = *(const float2*)(x + (size_t)ix[k] * DIM + ch);
        a0 += v.x; a1 += v.y;
      }
    }
    for (; j < end; ++j) {
      float2 v = *(const float2*)(x + (size_t)csr_col[j] * DIM + ch);
      a0 += v.x; a1 += v.y;
    }
  }
  unsigned o = (unsigned)f2bf(a0) | ((unsigned)f2bf(a1) << 16);
  *(unsigned*)(agg + (size_t)node * DIM + ch) = o;
}

// ================= MFMA GEMM (16B-wide stage, +BN in, +stats out) ========
__global__ __launch_bounds__(256) void gemm_kernel(
    const void* __restrict__ Ap, const unsigned short* __restrict__ agg,
    const unsigned short* __restrict__ PWm, const float* __restrict__ bias,
    const float* __restrict__ stats_in, const float* __restrict__ gv,
    const float* __restrict__ bev, void* __restrict__ Cp,
    float* __restrict__ stats_out, const int* __restrict__ flagp,
    int a_ext, int add_agg, int out_ext) {
  __shared__ unsigned short As[64 * 136];
  __shared__ float red_s[256];
  __shared__ float red_q[256];
  __shared__ float ssl[256];
  const int tid = threadIdx.x;
  const int row0 = blockIdx.x * 64;
  const int bf = *flagp;
  const int has_tf = (stats_in != nullptr);

  if (has_tf) {
    if (tid < 128) {
      float s = 0.f, q = 0.f;
#pragma unroll
      for (int k = 0; k < NSLOT; ++k) {
        s += stats_in[k * 256 + tid];
        q += stats_in[k * 256 + 128 + tid];
      }
      const float invN = 1.0f / (float)N_NODES;
      float m = s * invN;
      float v = q * invN - m * m;
      float scv = gv[tid] * rsqrtf(v + BN_EPS);
      ssl[tid] = scv;
      ssl[128 + tid] = bev[tid] - m * scv;
    }
    __syncthreads();
  }

  // stage: 16B per lane per iteration (4 iterations cover 64x128 bf16)
  for (int i = 0; i < 4; ++i) {
    int G = tid + i * 256;
    int lrow = G >> 4;
    int ch = (G & 15) * 8;
    int grow = row0 + lrow;
    float f[8];
    if (grow < N_NODES) {
      if (a_ext && !bf) {
        const float* xr = (const float*)Ap + (size_t)grow * DIM + ch;
        float4 v0 = *(const float4*)xr;
        float4 v1 = *(const float4*)(xr + 4);
        f[0] = v0.x; f[1] = v0.y; f[2] = v0.z; f[3] = v0.w;
        f[4] = v1.x; f[5] = v1.y; f[6] = v1.z; f[7] = v1.w;
      } else {
        u16x8 u = *(const u16x8*)((const unsigned short*)Ap +
                                  (size_t)grow * DIM + ch);
#pragma unroll
        for (int k = 0; k < 8; ++k) f[k] = bf2f(u[k]);
      }
      if (has_tf) {
#pragma unroll
        for (int k = 0; k < 8; ++k)
          f[k] = fmaxf(f[k] * ssl[ch + k] + ssl[128 + ch + k], 0.f);
      }
      if (add_agg) {
        u16x8 au = *(const u16x8*)(agg + (size_t)grow * DIM + ch);
#pragma unroll
        for (int k = 0; k < 8; ++k) f[k] += bf2f(au[k]);
      }
    } else {
#pragma unroll
      for (int k = 0; k < 8; ++k) f[k] = 0.f;
    }
    u16x8 o;
#pragma unroll
    for (int k = 0; k < 8; ++k) o[k] = f2bf(f[k]);
    *(u16x8*)&As[lrow * 136 + ch] = o;
  }
  __syncthreads();

  const int wv = tid >> 6, lane = tid & 63;
  const int quad = lane >> 4, lo = lane & 15;
  accf4 acc[8];
#pragma unroll
  for (int nt = 0; nt < 8; ++nt) {
    acc[nt][0] = 0.f; acc[nt][1] = 0.f; acc[nt][2] = 0.f; acc[nt][3] = 0.f;
  }
#pragma unroll
  for (int kt = 0; kt < 4; ++kt) {
    bfrag8 a = *(const bfrag8*)&As[(wv * 16 + lo) * 136 + kt * 32 + quad * 8];
    const unsigned short* pw = PWm + kt * 4096 + lane * 8;
#pragma unroll
    for (int nt = 0; nt < 8; ++nt) {
      bfrag8 b = *(const bfrag8*)(pw + nt * 512);
      acc[nt] = __builtin_amdgcn_mfma_f32_16x16x32_bf16(a, b, acc[nt], 0, 0, 0);
    }
  }
  __syncthreads();

  if (out_ext && !bf) {
    float* Co = (float*)Cp;
#pragma unroll
    for (int nt = 0; nt < 8; ++nt) {
      float b = bias[nt * 16 + lo];
#pragma unroll
      for (int reg = 0; reg < 4; ++reg) {
        int grow = row0 + wv * 16 + quad * 4 + reg;
        if (grow < N_NODES)
          Co[(size_t)grow * DIM + nt * 16 + lo] = acc[nt][reg] + b;
      }
    }
  } else {
#pragma unroll
    for (int nt = 0; nt < 8; ++nt) {
      float b = bias[nt * 16 + lo];
#pragma unroll
      for (int reg = 0; reg < 4; ++reg) {
        As[(wv * 16 + quad * 4 + reg) * 136 + nt * 16 + lo] =
            f2bf(acc[nt][reg] + b);
      }
    }
    __syncthreads();
    unsigned short* Co = (unsigned short*)Cp;
    for (int i = 0; i < 4; ++i) {
      int G = tid + i * 256;
      int lrow = G >> 4, ch = (G & 15) * 8;
      int grow = row0 + lrow;
      if (grow < N_NODES)
        *(u16x8*)(Co + (size_t)grow * DIM + ch) =
            *(const u16x8*)&As[lrow * 136 + ch];
    }
    if (stats_out) {
      int c = tid & 127, rh = tid >> 7;
      int rmax = N_NODES - row0;
      if (rmax > 64) rmax = 64;
      int rend = rh * 32 + 32;
      if (rend > rmax) rend = rmax;
      float s = 0.f, q = 0.f;
      for (int r = rh * 32; r < rend; ++r) {
        float v = bf2f(As[r * 136 + c]);
        s += v; q += v * v;
      }
      red_s[tid] = s; red_q[tid] = q;
      __syncthreads();
      if (tid < 128) {
        float* so = stats_out + (size_t)(blockIdx.x & (NSLOT - 1)) * 256;
        atomicAdd(so + tid, red_s[tid] + red_s[tid + 128]);
        atomicAdd(so + 128 + tid, red_q[tid] + red_q[tid + 128]);
      }
    }
  }
}

extern "C" void kernel_launch(void* const* d_in, const int* in_sizes, int n_in,
                              void* d_out, int out_size, void* d_ws, size_t ws_size,
                              hipStream_t stream) {
  const void* x  = d_in[0];
  const int* row = (const int*)d_in[1];
  const int* col = (const int*)d_in[2];

  const size_t ND = (size_t)N_NODES * DIM;
  unsigned short* agg = (unsigned short*)d_ws;        // ND bf16
  unsigned short* hA  = agg + ND;                     // ND bf16
  unsigned short* hB  = hA + ND;                      // ND bf16
  unsigned short* PW  = hB + ND;                      // 4*16384 bf16
  float* PV    = (float*)(PW + 4 * 16384);            // 10*128 fp32
  float* ps2   = PV + 10 * DIM;                       // 3*NSLOT*256 fp32
  int*   flag  = (int*)(ps2 + 3 * NSLOT * 256);       // 1 (+pad)
  int*   bcnt  = flag + 4;                            // NBUCK   (contiguous
  int*   gcur  = bcnt + NBUCK;                        // NBUCK    zero range)
  int*   offs  = gcur + NBUCK;                        // N+1
  int*   csr_col = offs + N_NODES + 1;                // E
  unsigned* ebuf = (unsigned*)(csr_col + N_EDGES);    // NBUCK*BCAP u32

  float* S0 = ps2 + 0 * NSLOT * 256;
  float* S1 = ps2 + 1 * NSLOT * 256;
  float* S2 = ps2 + 2 * NSLOT * 256;

  float* c0_b1f = PV + 0 * DIM; float* c0_gf  = PV + 1 * DIM;
  float* c0_bef = PV + 2 * DIM; float* c0_b2f = PV + 3 * DIM;
  float* bn0_gf = PV + 4 * DIM; float* bn0_bef= PV + 5 * DIM;
  float* c1_b1f = PV + 6 * DIM; float* c1_gf  = PV + 7 * DIM;
  float* c1_bef = PV + 8 * DIM; float* c1_b2f = PV + 9 * DIM;

  const int grow_grid = (N_NODES + 3) / 4;  // 12500

  PPtrs pp;
  pp.xs = x;
  pp.w[0] = d_in[3];  pp.w[1] = d_in[7];  pp.w[2] = d_in[11]; pp.w[3] = d_in[15];
  pp.v[0] = d_in[4];  pp.v[1] = d_in[5];  pp.v[2] = d_in[6];  pp.v[3] = d_in[8];
  pp.v[4] = d_in[9];  pp.v[5] = d_in[10]; pp.v[6] = d_in[12]; pp.v[7] = d_in[13];
  pp.v[8] = d_in[14]; pp.v[9] = d_in[16];

  // zero bcnt/gcur (2KB), then merged binA+prep
  hipMemsetAsync(bcnt, 0, 2 * NBUCK * sizeof(int), stream);
  binA_kernel<<<BINA_BLOCKS + 33, 256, 0, stream>>>(
      row, col, bcnt, gcur, ebuf, pp, PW, PV, flag, ps2);
  binB_kernel<<<NBUCK, 256, 0, stream>>>(bcnt, ebuf, csr_col, offs);

  // ---- conv0 ----
  gather_row_kernel<<<grow_grid, 256, 0, stream>>>(
      x, offs, csr_col, nullptr, nullptr, nullptr, agg, flag, 0);
  gemm_kernel<<<GEMM_GRID, 256, 0, stream>>>(
      x, agg, PW + 0 * 16384, c0_b1f, nullptr, nullptr, nullptr,
      hA, S0, flag, 1, 1, 0);
  gemm_kernel<<<GEMM_GRID, 256, 0, stream>>>(
      hA, nullptr, PW + 1 * 16384, c0_b2f, S0, c0_gf, c0_bef,
      hB, S1, flag, 0, 0, 0);

  // ---- conv1 ----
  gather_row_kernel<<<grow_grid, 256, 0, stream>>>(
      hB, offs, csr_col, S1, bn0_gf, bn0_bef, agg, flag, 1);
  gemm_kernel<<<GEMM_GRID, 256, 0, stream>>>(
      hB, agg, PW + 2 * 16384, c1_b1f, S1, bn0_gf, bn0_bef,
      hA, S2, flag, 0, 1, 0);
  gemm_kernel<<<GEMM_GRID, 256, 0, stream>>>(
      hA, nullptr, PW + 3 * 16384, c1_b2f, S2, c1_gf, c1_bef,
      d_out, nullptr, flag, 0, 0, 1);
}